// Round 1
// baseline (273.626 us; speedup 1.0000x reference)
//
#include <hip/hip_runtime.h>
#include <math.h>

// Problem constants (B,T,C)=(16,2048,1024), H=16, K=31, R=C/H=64, causal pad P=30.
#define TPB 256
#define KW  31
#define TT  93   // 3*KW outputs per thread per block
constexpr int B_ = 16, T_ = 2048, C_ = 1024, H_ = 16;

// out[b,t,c] = sum_{k=0..30} w[h,k] * x[b, t-30+k, c]
//            = sum_{j=0..30} w_rev[h,j] * x[b, t-j, c],  w_rev[j] = w[30-j]

__global__ void softmax_rev_kernel(const float* __restrict__ w, float* __restrict__ wr) {
    int h = threadIdx.x;
    if (h < H_) {
        float v[KW];
        float m = -1e30f;
        #pragma unroll
        for (int k = 0; k < KW; ++k) { v[k] = w[h * KW + k]; m = fmaxf(m, v[k]); }
        float s = 0.f;
        #pragma unroll
        for (int k = 0; k < KW; ++k) { v[k] = expf(v[k] - m); s += v[k]; }
        float inv = 1.f / s;
        #pragma unroll
        for (int k = 0; k < KW; ++k) wr[h * KW + (KW - 1 - k)] = v[k] * inv;
    }
}

__global__ void lconv_kernel(const float2* __restrict__ x,
                             const float* __restrict__ wr,
                             float2* __restrict__ out) {
    const int C2 = C_ / 2;
    const int c2 = blockIdx.x * TPB + threadIdx.x;   // float2 channel-pair index
    const int h  = c2 >> 5;                           // (2*c2)/64
    const int b  = blockIdx.z;
    const int t0 = blockIdx.y * TT;

    // weights (broadcast within wave — all 64 lanes share a head)
    float wv[KW];
    #pragma unroll
    for (int j = 0; j < KW; ++j) wv[j] = wr[h * KW + j];

    const float2* px = x   + (size_t)b * T_ * C2 + c2;
    float2*       po = out + (size_t)b * T_ * C2 + c2;

    // register window: invariant before a group with base tb: xw[s] = x[tb-31+s]
    float2 xw[KW];
    #pragma unroll
    for (int s = 0; s < KW; ++s) {
        int t = t0 - KW + s;
        float2 v = make_float2(0.f, 0.f);
        if (t >= 0) v = px[(size_t)t * C2];
        xw[s] = v;
    }

    for (int g = 0; g < TT / KW; ++g) {
        const int tb = t0 + g * KW;
        if (tb >= T_) break;                    // uniform across block
        if (tb + KW <= T_) {
            // fast path: no bounds checks
            #pragma unroll
            for (int s = 0; s < KW; ++s) {
                const int t = tb + s;
                float2 v = px[(size_t)t * C2];
                xw[s] = v;
                float ax = 0.f, ay = 0.f;
                #pragma unroll
                for (int j = 0; j < KW; ++j) {
                    int idx = s - j; if (idx < 0) idx += KW;   // compile-time constant
                    ax = fmaf(wv[j], xw[idx].x, ax);
                    ay = fmaf(wv[j], xw[idx].y, ay);
                }
                po[(size_t)t * C2] = make_float2(ax, ay);
            }
        } else {
            // tail path: guarded
            #pragma unroll
            for (int s = 0; s < KW; ++s) {
                const int t = tb + s;
                const bool ok = (t < T_);
                float2 v = make_float2(0.f, 0.f);
                if (ok) v = px[(size_t)t * C2];
                xw[s] = v;
                float ax = 0.f, ay = 0.f;
                #pragma unroll
                for (int j = 0; j < KW; ++j) {
                    int idx = s - j; if (idx < 0) idx += KW;
                    ax = fmaf(wv[j], xw[idx].x, ax);
                    ay = fmaf(wv[j], xw[idx].y, ay);
                }
                if (ok) po[(size_t)t * C2] = make_float2(ax, ay);
            }
        }
    }
}

extern "C" void kernel_launch(void* const* d_in, const int* in_sizes, int n_in,
                              void* d_out, int out_size, void* d_ws, size_t ws_size,
                              hipStream_t stream) {
    const float* x = (const float*)d_in[0];
    const float* w = (const float*)d_in[1];
    float* out = (float*)d_out;
    float* wr  = (float*)d_ws;   // H*KW = 496 floats

    hipLaunchKernelGGL(softmax_rev_kernel, dim3(1), dim3(64), 0, stream, w, wr);

    dim3 grid(C_ / (TPB * 2), (T_ + TT - 1) / TT, B_);   // (2, 23, 16)
    hipLaunchKernelGGL(lconv_kernel, grid, dim3(TPB), 0, stream,
                       (const float2*)x, wr, (float2*)out);
}

// Round 2
// 67.681 us; speedup vs baseline: 4.0429x; 4.0429x over previous
//
#include <hip/hip_runtime.h>
#include <math.h>

// (B,T,C)=(16,2048,1024), H=16, K=31, R=64, causal pad P=30.
// out[b,t,c] = sum_{j=0..30} w_rev[h(c),j] * x[b,t-j,c],  w_rev[j] = softmax(w)[30-j]
#define TPB 256
#define KW  31
constexpr int B_ = 16, T_ = 2048, C_ = 1024, H_ = 16;

__global__ void softmax_rev_kernel(const float* __restrict__ w, float* __restrict__ wr) {
    int h = threadIdx.x;
    if (h < H_) {
        float v[KW];
        float m = -1e30f;
        #pragma unroll
        for (int k = 0; k < KW; ++k) { v[k] = w[h * KW + k]; m = fmaxf(m, v[k]); }
        float s = 0.f;
        #pragma unroll
        for (int k = 0; k < KW; ++k) { v[k] = expf(v[k] - m); s += v[k]; }
        float inv = 1.f / s;
        #pragma unroll
        for (int k = 0; k < KW; ++k) wr[h * KW + (KW - 1 - k)] = v[k] * inv;
    }
}

// One 31-row window pass per thread. Fully unrolled: every window index is a
// compile-time constant -> xw[] stays in VGPRs (round-1 version spilled).
__global__ __launch_bounds__(TPB) void lconv_kernel(const float2* __restrict__ x,
                                                    const float* __restrict__ wr,
                                                    float2* __restrict__ out) {
    const int C2 = C_ / 2;
    const int c2 = blockIdx.x * TPB + threadIdx.x;   // float2 channel-pair index
    const int h  = c2 >> 5;                          // both channels of the pair share a head
    const int b  = blockIdx.z;
    const int t0 = blockIdx.y * KW;

    float wv[KW];
    #pragma unroll
    for (int j = 0; j < KW; ++j) wv[j] = wr[h * KW + j];

    const float2* px = x   + (size_t)b * T_ * C2 + c2;
    float2*       po = out + (size_t)b * T_ * C2 + c2;

    // Prime window: xw[s] = x[t0-31+s]  (zero for t<0; only block y==0 needs guards)
    float2 xw[KW];
    if (blockIdx.y == 0) {
        #pragma unroll
        for (int s = 0; s < KW; ++s) xw[s] = make_float2(0.f, 0.f);
    } else {
        #pragma unroll
        for (int s = 0; s < KW; ++s) xw[s] = px[(size_t)(t0 - KW + s) * C2];
    }

    if (t0 + KW <= T_) {
        // interior: no bounds checks
        #pragma unroll
        for (int s = 0; s < KW; ++s) {
            const int t = t0 + s;
            xw[s] = px[(size_t)t * C2];
            float ax = 0.f, ay = 0.f;
            #pragma unroll
            for (int j = 0; j < KW; ++j) {
                int idx = s - j; if (idx < 0) idx += KW;   // static after unroll
                ax = fmaf(wv[j], xw[idx].x, ax);
                ay = fmaf(wv[j], xw[idx].y, ay);
            }
            po[(size_t)t * C2] = make_float2(ax, ay);
        }
    } else {
        // tail block: guarded
        #pragma unroll
        for (int s = 0; s < KW; ++s) {
            const int t = t0 + s;
            const bool ok = (t < T_);
            float2 v = make_float2(0.f, 0.f);
            if (ok) v = px[(size_t)t * C2];
            xw[s] = v;
            float ax = 0.f, ay = 0.f;
            #pragma unroll
            for (int j = 0; j < KW; ++j) {
                int idx = s - j; if (idx < 0) idx += KW;
                ax = fmaf(wv[j], xw[idx].x, ax);
                ay = fmaf(wv[j], xw[idx].y, ay);
            }
            if (ok) po[(size_t)t * C2] = make_float2(ax, ay);
        }
    }
}

extern "C" void kernel_launch(void* const* d_in, const int* in_sizes, int n_in,
                              void* d_out, int out_size, void* d_ws, size_t ws_size,
                              hipStream_t stream) {
    const float* x = (const float*)d_in[0];
    const float* w = (const float*)d_in[1];
    float* out = (float*)d_out;
    float* wr  = (float*)d_ws;   // H*KW = 496 floats

    hipLaunchKernelGGL(softmax_rev_kernel, dim3(1), dim3(64), 0, stream, w, wr);

    dim3 grid(C_ / (TPB * 2), (T_ + KW - 1) / KW, B_);   // (2, 67, 16)
    hipLaunchKernelGGL(lconv_kernel, grid, dim3(TPB), 0, stream,
                       (const float2*)x, wr, (float2*)out);
}